// Round 3
// baseline (348.825 us; speedup 1.0000x reference)
//
#include <hip/hip_runtime.h>
#include <hip/hip_bf16.h>

// axon_layer: dual-exponential PSP scan over T for B*F independent rows.
// All I/O fp32 (round-1 NaN proved inputs aren't bf16; round-2 error
// pattern 5.5625 == fp32-read-of-bf16-writes proved output is fp32).
// One wave (64 lanes) per row: lane l owns 8 consecutive timesteps
// (2x float4 loads/stores); blocked Kogge-Stone scan for the two linear
// recurrences m, s (decay multipliers are wave-uniform, so segment
// composition is scalar: add' = dm^d * add_prev + add).

typedef float float4v __attribute__((ext_vector_type(4)));

#define TDIM 400
#define FDIM 4096
#define ROWS_PER_BLOCK 4   // 256 threads = 4 waves = 4 rows

__global__ __launch_bounds__(256) void axon_scan_kernel(
    const float* __restrict__ x,        // [B*F, T]
    const float* __restrict__ decm,     // [F]
    const float* __restrict__ decs,     // [F]
    const float* __restrict__ v0p,      // [1]
    float* __restrict__ psp,            // [B*F, T]
    float* __restrict__ mT,             // [B*F]
    float* __restrict__ sT)             // [B*F]
{
    const int lane = threadIdx.x & 63;
    const int wave = threadIdx.x >> 6;
    const int row  = blockIdx.x * ROWS_PER_BLOCK + wave;
    const int f    = row & (FDIM - 1);

    const float dm = decm[f];
    const float ds = decs[f];
    const float v0 = v0p[0];

    const size_t rowoff = (size_t)row * TDIM;

    // --- load: lane l gets timesteps [8l, 8l+8); lanes >= 50 idle
    const bool active = (lane < TDIM / 8);  // lane < 50
    float xv[8];
    #pragma unroll
    for (int k = 0; k < 8; ++k) xv[k] = 0.f;
    if (active) {
        float4v a = *(const float4v*)(x + rowoff + (size_t)lane * 8);
        float4v b = *(const float4v*)(x + rowoff + (size_t)lane * 8 + 4);
        xv[0] = a.x; xv[1] = a.y; xv[2] = a.z; xv[3] = a.w;
        xv[4] = b.x; xv[5] = b.y; xv[6] = b.z; xv[7] = b.w;
    }

    // --- local (per-lane) sequential scan of 8 steps, zero-seeded
    float m = 0.f, s = 0.f;
    #pragma unroll
    for (int k = 0; k < 8; ++k) {
        m = fmaf(m, dm, xv[k]);
        s = fmaf(s, ds, xv[k]);
    }

    // --- cross-lane Kogge-Stone inclusive scan of segment finals
    // multiplier starts at dm^8 / ds^8, squared each step
    float am = dm * dm; am = am * am; am = am * am;   // dm^8
    float as_ = ds * ds; as_ = as_ * as_; as_ = as_ * as_;
    float cm = m, cs = s;
    #pragma unroll
    for (int d = 1; d < 64; d <<= 1) {
        float um = __shfl_up(cm, (unsigned)d, 64);
        float us = __shfl_up(cs, (unsigned)d, 64);
        if (lane >= d) {
            cm = fmaf(am, um, cm);
            cs = fmaf(as_, us, cs);
        }
        am *= am;
        as_ *= as_;
    }

    // --- exclusive carry into this lane's segment
    float em = __shfl_up(cm, 1u, 64);
    float es = __shfl_up(cs, 1u, 64);
    if (lane == 0) { em = 0.f; es = 0.f; }

    // --- seeded re-scan: final m,s per timestep; psp = (m-s)*v0
    float4v oa, ob;
    m = em; s = es;
    #pragma unroll
    for (int k = 0; k < 8; ++k) {
        m = fmaf(m, dm, xv[k]);
        s = fmaf(s, ds, xv[k]);
        float p = (m - s) * v0;
        if (k < 4) oa[k] = p; else ob[k - 4] = p;
    }
    if (active) {
        *(float4v*)(psp + rowoff + (size_t)lane * 8)     = oa;
        *(float4v*)(psp + rowoff + (size_t)lane * 8 + 4) = ob;
    }

    // --- final states live at lane 49 (timestep 399)
    float mTv = __shfl(m, 49, 64);
    float sTv = __shfl(s, 49, 64);
    if (lane == 0) {
        mT[row] = mTv;
        sT[row] = sTv;
    }
}

extern "C" void kernel_launch(void* const* d_in, const int* in_sizes, int n_in,
                              void* d_out, int out_size, void* d_ws, size_t ws_size,
                              hipStream_t stream) {
    const float* x    = (const float*)d_in[0];
    const float* decm = (const float*)d_in[1];
    const float* decs = (const float*)d_in[2];
    const float* v0p  = (const float*)d_in[3];

    float* out = (float*)d_out;
    const size_t BF = (size_t)in_sizes[0] / TDIM;   // 131072 rows
    float* psp = out;
    float* mTp = out + BF * (size_t)TDIM;
    float* sTp = mTp + BF;

    dim3 grid((unsigned)(BF / ROWS_PER_BLOCK));     // 32768 blocks
    dim3 block(256);
    hipLaunchKernelGGL(axon_scan_kernel, grid, block, 0, stream,
                       x, decm, decs, v0p, psp, mTp, sTp);
}